// Round 1
// baseline (2968.710 us; speedup 1.0000x reference)
//
#include <hip/hip_runtime.h>
#include <math.h>

// ---------------------------------------------------------------------------
// Feature extraction: per-node fused conv1(1->32,3x3,pad1) + ReLU +
// conv2(32->64,2x2,pad1) + ReLU + overlapping 2x2 adaptive pool + fc(256->32).
// One block (256 threads) per node; everything stays in LDS.
// ---------------------------------------------------------------------------
__global__ __launch_bounds__(256) void fe_kernel(
    const float* __restrict__ x,
    const float* __restrict__ w1, const float* __restrict__ b1,
    const float* __restrict__ w2, const float* __restrict__ b2,
    const float* __restrict__ fw, const float* __restrict__ fb,
    float* __restrict__ sig, int n)
{
    __shared__ float xs[100];          // 10x10 zero-padded input
    __shared__ float h1p[32][100];     // conv1 out, zero-padded 10x10 per channel
    __shared__ float w2s[64][132];     // conv2 weights, row padded 128->132 (bank spread)
    __shared__ float pool[256];        // pooled 64ch x 2 x 2
    __shared__ float red[8][32];       // fc partial sums

    const int node = blockIdx.x;
    const int t = threadIdx.x;

    // stage conv2 weights into LDS
    for (int e = t; e < 8192; e += 256)
        w2s[e >> 7][e & 127] = w2[e];
    if (t < 100) xs[t] = 0.0f;
    pool[t] = 0.0f;
    for (int e = t; e < 3200; e += 256)
        (&h1p[0][0])[e] = 0.0f;
    __syncthreads();

    if (t < 64) {
        int i = t >> 3, j = t & 7;
        xs[(i + 1) * 10 + (j + 1)] = x[(size_t)node * 64 + t];
    }
    __syncthreads();

    // conv1: thread t -> channel c = t>>3, column j = t&7, all 8 rows
    {
        const int c = t >> 3, j = t & 7;
        float wr[9];
        #pragma unroll
        for (int q = 0; q < 9; ++q) wr[q] = w1[c * 9 + q];
        const float bb = b1[c];
        #pragma unroll
        for (int i = 0; i < 8; ++i) {
            float s = bb;
            #pragma unroll
            for (int ki = 0; ki < 3; ++ki)
                #pragma unroll
                for (int kj = 0; kj < 3; ++kj)
                    s = fmaf(xs[(i + ki) * 10 + (j + kj)], wr[ki * 3 + kj], s);
            h1p[c][(i + 1) * 10 + (j + 1)] = fmaxf(s, 0.0f);
        }
    }
    __syncthreads();

    // conv2 (9x9 out) + ReLU + overlapping pool (means over rows/cols {0..4},{4..8})
    // thread owns c_outs {c0, c0+16, c0+32, c0+48}, pixels p = ps + 16*m
    {
        const int c0 = t & 15;
        const int ps = t >> 4;
        int pi[6], pj[6]; bool pv[6];
        #pragma unroll
        for (int m = 0; m < 6; ++m) {
            int p = ps + 16 * m;
            pv[m] = (p < 81);
            int ii = p / 9;
            pi[m] = ii; pj[m] = p - ii * 9;
        }
        float s[6][4];
        #pragma unroll
        for (int m = 0; m < 6; ++m)
            #pragma unroll
            for (int g = 0; g < 4; ++g) s[m][g] = b2[c0 + g * 16];

        for (int ci = 0; ci < 32; ++ci) {
            float4 w[4];
            #pragma unroll
            for (int g = 0; g < 4; ++g)
                w[g] = *reinterpret_cast<const float4*>(&w2s[c0 + g * 16][ci * 4]);
            const float* hrow = &h1p[ci][0];
            #pragma unroll
            for (int m = 0; m < 6; ++m) {
                if (!pv[m]) continue;
                const float* pp = hrow + pi[m] * 10 + pj[m];
                const float a00 = pp[0], a01 = pp[1], a10 = pp[10], a11 = pp[11];
                #pragma unroll
                for (int g = 0; g < 4; ++g) {
                    s[m][g] = fmaf(a00, w[g].x, s[m][g]);
                    s[m][g] = fmaf(a01, w[g].y, s[m][g]);
                    s[m][g] = fmaf(a10, w[g].z, s[m][g]);
                    s[m][g] = fmaf(a11, w[g].w, s[m][g]);
                }
            }
        }
        #pragma unroll
        for (int m = 0; m < 6; ++m) {
            if (!pv[m]) continue;
            const int i = pi[m], j = pj[m];
            #pragma unroll
            for (int g = 0; g < 4; ++g) {
                const int c = c0 + g * 16;
                const float v = fmaxf(s[m][g], 0.0f) * 0.04f;  // /25
                if (i <= 4) {
                    if (j <= 4) atomicAdd(&pool[c * 4 + 0], v);
                    if (j >= 4) atomicAdd(&pool[c * 4 + 1], v);
                }
                if (i >= 4) {
                    if (j <= 4) atomicAdd(&pool[c * 4 + 2], v);
                    if (j >= 4) atomicAdd(&pool[c * 4 + 3], v);
                }
            }
        }
    }
    __syncthreads();

    // fc: 256 -> 32
    {
        const int o = t & 31, chunk = t >> 5;
        float partial = 0.0f;
        #pragma unroll
        for (int kk = 0; kk < 32; ++kk) {
            int k = chunk * 32 + kk;
            partial = fmaf(pool[k], fw[k * 32 + o], partial);
        }
        red[chunk][o] = partial;
    }
    __syncthreads();
    if (t < 32) {
        float s = fb[t];
        #pragma unroll
        for (int ch = 0; ch < 8; ++ch) s += red[ch][t];
        sig[(size_t)node * 32 + t] = s;
    }
}

// ---------------------------------------------------------------------------
__global__ void zero_k(float* __restrict__ p, int n)
{
    int i = blockIdx.x * blockDim.x + threadIdx.x;
    if (i < n) p[i] = 0.0f;
}

__global__ void count_k(const int* __restrict__ ei, float* __restrict__ outdeg,
                        float* __restrict__ indeg, int n)
{
    int e = blockIdx.x * blockDim.x + threadIdx.x;
    if (e >= n) return;
    atomicAdd(&outdeg[ei[e]], 1.0f);
    atomicAdd(&indeg[ei[n + e]], 1.0f);
}

__global__ void prep_k(const float* __restrict__ indeg, float* __restrict__ dis, int n)
{
    int i = blockIdx.x * blockDim.x + threadIdx.x;
    if (i < n) dis[i] = rsqrtf(indeg[i] + 1.0f);   // deg includes self-loop, >= 1
}

__global__ void att_k(const float* __restrict__ aux, const int* __restrict__ ei,
                      const float* __restrict__ outdeg,
                      float* __restrict__ att1, float* __restrict__ att2, int n)
{
    int e = blockIdx.x * blockDim.x + threadIdx.x;
    if (e >= n) return;
    const int s = ei[e], d = ei[n + e];
    const float fs = aux[(size_t)s * 3 + 2], fdd = aux[(size_t)d * 3 + 2];
    const float fd = fabsf(fs - fdd);
    att1[e] = (fd == 1.0f) ? (1.0f / fmaxf(outdeg[s], 1.0f)) : 0.0f;
    const float angs = aux[(size_t)s * 3 + 0], rads = aux[(size_t)s * 3 + 1];
    const float angd = aux[(size_t)d * 3 + 0], radd = aux[(size_t)d * 3 + 1];
    const float dx = radd * cosf(angd) - rads * cosf(angs);
    const float dy = radd * sinf(angd) - rads * sinf(angs);
    const float vel = sqrtf(dx * dx + dy * dy + 1e-12f) * 0.5f;   // fd_safe = 2
    att2[e] = (fd == 2.0f) ? expf(-vel / 8.5f) : 0.0f;
}

// Y[n,64] = X[n,K] @ W[K,64]
__global__ void mm_k(const float* __restrict__ X, const float* __restrict__ W,
                     float* __restrict__ Y, int n, int K)
{
    size_t idx = (size_t)blockIdx.x * blockDim.x + threadIdx.x;
    if (idx >= (size_t)n * 64) return;
    const int node = (int)(idx >> 6), o = (int)(idx & 63);
    const float* xr = X + (size_t)node * K;
    float s = 0.0f;
    for (int k = 0; k < K; ++k) s = fmaf(xr[k], W[k * 64 + o], s);
    Y[idx] = s;
}

// acc = bias + dis^2 * h  (self-loop term)
__global__ void accinit_k(const float* __restrict__ h, const float* __restrict__ dis,
                          const float* __restrict__ b, float* __restrict__ acc, int n)
{
    size_t idx = (size_t)blockIdx.x * blockDim.x + threadIdx.x;
    if (idx >= (size_t)n * 64) return;
    const int node = (int)(idx >> 6), k = (int)(idx & 63);
    const float di = dis[node];
    acc[idx] = b[k] + di * di * h[idx];
}

__global__ void scatter_k(const float* __restrict__ h, const int* __restrict__ ei,
                          const float* __restrict__ dis, float* __restrict__ acc, int n)
{
    size_t idx = (size_t)blockIdx.x * blockDim.x + threadIdx.x;
    if (idx >= (size_t)n * 64) return;
    const int e = (int)(idx >> 6), k = (int)(idx & 63);
    const int s = ei[e], d = ei[n + e];
    const float w = dis[s] * dis[d];
    atomicAdd(&acc[(size_t)d * 64 + k], w * h[(size_t)s * 64 + k]);
}

// acc = relu(acc * att[node])
__global__ void fin_k(float* __restrict__ acc, const float* __restrict__ att, int n)
{
    size_t idx = (size_t)blockIdx.x * blockDim.x + threadIdx.x;
    if (idx >= (size_t)n * 64) return;
    const int node = (int)(idx >> 6);
    acc[idx] = fmaxf(acc[idx] * att[node], 0.0f);
}

// head: relu(x2 @ fc_w + fc_b) @ out_w + out_b -> sigmoid
__global__ void head_k(const float* __restrict__ x2, const float* __restrict__ fcw,
                       const float* __restrict__ fcb, const float* __restrict__ outw,
                       const float* __restrict__ outb, float* __restrict__ out, int n)
{
    size_t idx = (size_t)blockIdx.x * blockDim.x + threadIdx.x;
    const int node = (int)(idx >> 5), o = (int)(idx & 31);
    if (node >= n) return;
    const float* xr = x2 + (size_t)node * 64;
    float s = fcb[o];
    #pragma unroll
    for (int k = 0; k < 64; ++k) s = fmaf(xr[k], fcw[k * 32 + o], s);
    s = fmaxf(s, 0.0f);
    float p = s * outw[o];
    #pragma unroll
    for (int m = 16; m >= 1; m >>= 1) p += __shfl_xor(p, m);
    if (o == 0) out[node] = 1.0f / (1.0f + expf(-(p + outb[0])));
}

// ---------------------------------------------------------------------------
extern "C" void kernel_launch(void* const* d_in, const int* in_sizes, int n_in,
                              void* d_out, int out_size, void* d_ws, size_t ws_size,
                              hipStream_t stream)
{
    const float* x    = (const float*)d_in[0];
    const float* aux  = (const float*)d_in[1];
    const int*   ei   = (const int*)  d_in[2];
    const float* c1w  = (const float*)d_in[3];
    const float* c1b  = (const float*)d_in[4];
    const float* c2w  = (const float*)d_in[5];
    const float* c2b  = (const float*)d_in[6];
    const float* few  = (const float*)d_in[7];
    const float* feb  = (const float*)d_in[8];
    const float* g1w  = (const float*)d_in[9];
    const float* g1b  = (const float*)d_in[10];
    const float* g2w  = (const float*)d_in[11];
    const float* g2b  = (const float*)d_in[12];
    const float* fcw  = (const float*)d_in[13];
    const float* fcb  = (const float*)d_in[14];
    const float* outw = (const float*)d_in[15];
    const float* outb = (const float*)d_in[16];
    float* out = (float*)d_out;

    const int n = in_sizes[0] / 64;

    float* ws     = (float*)d_ws;
    float* sig    = ws;                          // n*32
    float* h      = sig + (size_t)n * 32;        // n*64
    float* acc    = h   + (size_t)n * 64;        // n*64
    float* outdeg = acc + (size_t)n * 64;        // n
    float* indeg  = outdeg + n;                  // n
    float* dis    = indeg + n;                   // n
    float* att1   = dis + n;                     // n
    float* att2   = att1 + n;                    // n

    const dim3 b256(256);
    const int gN  = (n + 255) / 256;
    const int gNM = (int)(((size_t)n * 64 + 255) / 256);
    const int gNH = (int)(((size_t)n * 32 + 255) / 256);

    fe_kernel<<<n, b256, 0, stream>>>(x, c1w, c1b, c2w, c2b, few, feb, sig, n);

    zero_k<<<(2 * n + 255) / 256, b256, 0, stream>>>(outdeg, 2 * n);
    count_k<<<gN, b256, 0, stream>>>(ei, outdeg, indeg, n);
    prep_k<<<gN, b256, 0, stream>>>(indeg, dis, n);
    att_k<<<gN, b256, 0, stream>>>(aux, ei, outdeg, att1, att2, n);

    // GCN layer 1
    mm_k<<<gNM, b256, 0, stream>>>(sig, g1w, h, n, 32);
    accinit_k<<<gNM, b256, 0, stream>>>(h, dis, g1b, acc, n);
    scatter_k<<<gNM, b256, 0, stream>>>(h, ei, dis, acc, n);
    fin_k<<<gNM, b256, 0, stream>>>(acc, att1, n);

    // GCN layer 2
    mm_k<<<gNM, b256, 0, stream>>>(acc, g2w, h, n, 64);
    accinit_k<<<gNM, b256, 0, stream>>>(h, dis, g2b, acc, n);
    scatter_k<<<gNM, b256, 0, stream>>>(h, ei, dis, acc, n);
    fin_k<<<gNM, b256, 0, stream>>>(acc, att2, n);

    head_k<<<gNH, b256, 0, stream>>>(acc, fcw, fcb, outw, outb, out, n);
}

// Round 2
// 935.096 us; speedup vs baseline: 3.1748x; 3.1748x over previous
//
#include <hip/hip_runtime.h>
#include <hip/hip_bf16.h>
#include <math.h>

typedef float f32x4 __attribute__((ext_vector_type(4)));
typedef __bf16 bf16x8 __attribute__((ext_vector_type(8)));
typedef unsigned short ushort8 __attribute__((ext_vector_type(8)));
typedef unsigned short ushort4v __attribute__((ext_vector_type(4)));

static __device__ __forceinline__ unsigned short f2bf(float f) {
    return __builtin_bit_cast(unsigned short, __float2bfloat16(f));
}

// ---------------------------------------------------------------------------
// Feature extraction, MFMA version.
// conv1 (fp32, VALU) -> hT[pixel][ci] bf16 (row stride 40 ushorts = 80B)
// conv2 as 4 tap-GEMMs of K=32 via mfma_f32_16x16x32_bf16, M=96 (81 valid
// pixels), N=64. Each wave owns one 16-wide c_out tile. Pool + fc fused.
// ---------------------------------------------------------------------------
__global__ __launch_bounds__(256) void fe_kernel(
    const float* __restrict__ x,
    const float* __restrict__ w1, const float* __restrict__ b1,
    const float* __restrict__ w2, const float* __restrict__ b2,
    const float* __restrict__ fw, const float* __restrict__ fb,
    float* __restrict__ sig, int n)
{
    __shared__ unsigned short hT[100][40];      // 10x10 padded pixels x 32 ci (+8 pad)
    __shared__ unsigned short w2T[4][64][40];   // [tap][co][ci], bf16
    __shared__ float xs[100];                   // padded input
    __shared__ float w1s[320];                  // conv1 w (288) + b (32)
    __shared__ float pool[256];                 // [co][bin]
    __shared__ float red[8][32];

    const int node = blockIdx.x;
    const int t = threadIdx.x;
    const int lane = t & 63;
    const int wave = t >> 6;

    // ---- phase 0: stage weights, load input, zero pad regions (disjoint) ----
    for (int e = t; e < 288; e += 256) w1s[e] = w1[e];
    if (t < 32) w1s[288 + t] = b1[t];

    for (int q = t; q < 2048; q += 256) {       // 4 bf16 per thread-iter
        const int tap = q >> 9;
        const int rem = q & 511;
        const int co  = rem >> 3;
        const int cq  = rem & 7;
        const float* gp = w2 + co * 128 + cq * 16 + tap;  // w2[co][ci][tap]
        ushort4v v;
        v.x = f2bf(gp[0]); v.y = f2bf(gp[4]); v.z = f2bf(gp[8]); v.w = f2bf(gp[12]);
        *reinterpret_cast<ushort4v*>(&w2T[tap][co][cq * 4]) = v;
    }

    if (t < 100) {
        const int pi = t / 10, pj = t - 10 * (t / 10);
        float v = 0.f;
        if (pi >= 1 && pi <= 8 && pj >= 1 && pj <= 8)
            v = x[(size_t)node * 64 + (pi - 1) * 8 + (pj - 1)];
        xs[t] = v;

        ushort8 z = {0, 0, 0, 0, 0, 0, 0, 0};
        *reinterpret_cast<ushort8*>(&hT[t][32]) = z;   // ci pad columns
        if (pi == 0 || pi == 9 || pj == 0 || pj == 9) { // spatial pad rows
            *reinterpret_cast<ushort8*>(&hT[t][0])  = z;
            *reinterpret_cast<ushort8*>(&hT[t][8])  = z;
            *reinterpret_cast<ushort8*>(&hT[t][16]) = z;
            *reinterpret_cast<ushort8*>(&hT[t][24]) = z;
        }
    }
    __syncthreads();

    // ---- phase 1: conv1 (thread = pixel x 8-channel group), write bf16 hT ----
    {
        const int p = lane;                  // 0..63
        const int i = p >> 3, j = p & 7;
        const int g = wave;                  // channels g*8 .. g*8+7
        float xv[9];
        #pragma unroll
        for (int ki = 0; ki < 3; ++ki)
            #pragma unroll
            for (int kj = 0; kj < 3; ++kj)
                xv[ki * 3 + kj] = xs[(i + ki) * 10 + (j + kj)];
        ushort8 outv;
        #pragma unroll
        for (int cc = 0; cc < 8; ++cc) {
            const int c = g * 8 + cc;
            float s = w1s[288 + c];
            #pragma unroll
            for (int q = 0; q < 9; ++q) s = fmaf(xv[q], w1s[c * 9 + q], s);
            outv[cc] = f2bf(fmaxf(s, 0.f));
        }
        *reinterpret_cast<ushort8*>(&hT[(i + 1) * 10 + (j + 1)][g * 8]) = outv;
    }
    __syncthreads();

    // ---- phase 2: conv2 via MFMA ----
    const int colane = lane & 15;
    const int kgrp = lane >> 4;
    const int co = (wave << 4) + colane;     // this wave's c_out
    const int ci0 = kgrp << 3;               // k-offset within 32-ci step

    bf16x8 bfr[4];
    #pragma unroll
    for (int tap = 0; tap < 4; ++tap)
        bfr[tap] = *reinterpret_cast<const bf16x8*>(&w2T[tap][co][ci0]);

    int rbase[6];
    #pragma unroll
    for (int m = 0; m < 6; ++m) {
        const int p = m * 16 + colane;       // A-side pixel row
        const int i = p / 9, j = p - 9 * i;
        rbase[m] = (p < 81) ? (i * 10 + j) : 0;   // invalid rows read zeros/garbage, unused
    }

    f32x4 acc[6];
    #pragma unroll
    for (int m = 0; m < 6; ++m) { f32x4 zz = {0.f, 0.f, 0.f, 0.f}; acc[m] = zz; }

    #pragma unroll
    for (int m = 0; m < 6; ++m) {
        #pragma unroll
        for (int tap = 0; tap < 4; ++tap) {
            const int r = rbase[m] + (tap >> 1) * 10 + (tap & 1);
            const bf16x8 afr = *reinterpret_cast<const bf16x8*>(&hT[r][ci0]);
            acc[m] = __builtin_amdgcn_mfma_f32_16x16x32_bf16(afr, bfr[tap], acc[m], 0, 0, 0);
        }
    }

    // ---- phase 3: bias + relu + overlapping 2x2 pool, in-register ----
    {
        float b0 = 0.f, b1v = 0.f, b2v_ = 0.f, b3 = 0.f;
        const float bias = b2[co];
        #pragma unroll
        for (int m = 0; m < 6; ++m) {
            #pragma unroll
            for (int rg = 0; rg < 4; ++rg) {
                const int p = m * 16 + (kgrp << 2) + rg;   // D-side pixel row
                if (p < 81) {
                    const int i = p / 9, j = p - 9 * i;
                    const float v = fmaxf(acc[m][rg] + bias, 0.f) * 0.04f;
                    if (i <= 4) { if (j <= 4) b0 += v; if (j >= 4) b1v += v; }
                    if (i >= 4) { if (j <= 4) b2v_ += v; if (j >= 4) b3 += v; }
                }
            }
        }
        b0   += __shfl_xor(b0, 16);   b0   += __shfl_xor(b0, 32);
        b1v  += __shfl_xor(b1v, 16);  b1v  += __shfl_xor(b1v, 32);
        b2v_ += __shfl_xor(b2v_, 16); b2v_ += __shfl_xor(b2v_, 32);
        b3   += __shfl_xor(b3, 16);   b3   += __shfl_xor(b3, 32);
        if (kgrp == 0) {
            pool[co * 4 + 0] = b0;
            pool[co * 4 + 1] = b1v;
            pool[co * 4 + 2] = b2v_;
            pool[co * 4 + 3] = b3;
        }
    }
    __syncthreads();

    // ---- phase 4: fc 256 -> 32 ----
    {
        const int o = t & 31, chunk = t >> 5;
        float partial = 0.0f;
        #pragma unroll
        for (int kk = 0; kk < 32; ++kk) {
            const int k = chunk * 32 + kk;
            partial = fmaf(pool[k], fw[k * 32 + o], partial);
        }
        red[chunk][o] = partial;
    }
    __syncthreads();
    if (t < 32) {
        float s = fb[t];
        #pragma unroll
        for (int ch = 0; ch < 8; ++ch) s += red[ch][t];
        sig[(size_t)node * 32 + t] = s;
    }
}

// ---------------------------------------------------------------------------
__global__ void zero_k(float* __restrict__ p, int n)
{
    int i = blockIdx.x * blockDim.x + threadIdx.x;
    if (i < n) p[i] = 0.0f;
}

__global__ void count_k(const int* __restrict__ ei, float* __restrict__ outdeg,
                        float* __restrict__ indeg, int n)
{
    int e = blockIdx.x * blockDim.x + threadIdx.x;
    if (e >= n) return;
    atomicAdd(&outdeg[ei[e]], 1.0f);
    atomicAdd(&indeg[ei[n + e]], 1.0f);
}

__global__ void prep_k(const float* __restrict__ indeg, float* __restrict__ dis, int n)
{
    int i = blockIdx.x * blockDim.x + threadIdx.x;
    if (i < n) dis[i] = rsqrtf(indeg[i] + 1.0f);
}

__global__ void att_k(const float* __restrict__ aux, const int* __restrict__ ei,
                      const float* __restrict__ outdeg,
                      float* __restrict__ att1, float* __restrict__ att2, int n)
{
    int e = blockIdx.x * blockDim.x + threadIdx.x;
    if (e >= n) return;
    const int s = ei[e], d = ei[n + e];
    const float fs = aux[(size_t)s * 3 + 2], fdd = aux[(size_t)d * 3 + 2];
    const float fd = fabsf(fs - fdd);
    att1[e] = (fd == 1.0f) ? (1.0f / fmaxf(outdeg[s], 1.0f)) : 0.0f;
    const float angs = aux[(size_t)s * 3 + 0], rads = aux[(size_t)s * 3 + 1];
    const float angd = aux[(size_t)d * 3 + 0], radd = aux[(size_t)d * 3 + 1];
    const float dx = radd * cosf(angd) - rads * cosf(angs);
    const float dy = radd * sinf(angd) - rads * sinf(angs);
    const float vel = sqrtf(dx * dx + dy * dy + 1e-12f) * 0.5f;
    att2[e] = (fd == 2.0f) ? expf(-vel / 8.5f) : 0.0f;
}

// Y[n,64] = X[n,K] @ W[K,64]
__global__ void mm_k(const float* __restrict__ X, const float* __restrict__ W,
                     float* __restrict__ Y, int n, int K)
{
    size_t idx = (size_t)blockIdx.x * blockDim.x + threadIdx.x;
    if (idx >= (size_t)n * 64) return;
    const int node = (int)(idx >> 6), o = (int)(idx & 63);
    const float* xr = X + (size_t)node * K;
    float s = 0.0f;
    for (int k = 0; k < K; ++k) s = fmaf(xr[k], W[k * 64 + o], s);
    Y[idx] = s;
}

__global__ void accinit_k(const float* __restrict__ h, const float* __restrict__ dis,
                          const float* __restrict__ b, float* __restrict__ acc, int n)
{
    size_t idx = (size_t)blockIdx.x * blockDim.x + threadIdx.x;
    if (idx >= (size_t)n * 64) return;
    const int node = (int)(idx >> 6), k = (int)(idx & 63);
    const float di = dis[node];
    acc[idx] = b[k] + di * di * h[idx];
}

__global__ void scatter_k(const float* __restrict__ h, const int* __restrict__ ei,
                          const float* __restrict__ dis, float* __restrict__ acc, int n)
{
    size_t idx = (size_t)blockIdx.x * blockDim.x + threadIdx.x;
    if (idx >= (size_t)n * 64) return;
    const int e = (int)(idx >> 6), k = (int)(idx & 63);
    const int s = ei[e], d = ei[n + e];
    const float w = dis[s] * dis[d];
    atomicAdd(&acc[(size_t)d * 64 + k], w * h[(size_t)s * 64 + k]);
}

__global__ void fin_k(float* __restrict__ acc, const float* __restrict__ att, int n)
{
    size_t idx = (size_t)blockIdx.x * blockDim.x + threadIdx.x;
    if (idx >= (size_t)n * 64) return;
    const int node = (int)(idx >> 6);
    acc[idx] = fmaxf(acc[idx] * att[node], 0.0f);
}

__global__ void head_k(const float* __restrict__ x2, const float* __restrict__ fcw,
                       const float* __restrict__ fcb, const float* __restrict__ outw,
                       const float* __restrict__ outb, float* __restrict__ out, int n)
{
    size_t idx = (size_t)blockIdx.x * blockDim.x + threadIdx.x;
    const int node = (int)(idx >> 5), o = (int)(idx & 31);
    if (node >= n) return;
    const float* xr = x2 + (size_t)node * 64;
    float s = fcb[o];
    #pragma unroll
    for (int k = 0; k < 64; ++k) s = fmaf(xr[k], fcw[k * 32 + o], s);
    s = fmaxf(s, 0.0f);
    float p = s * outw[o];
    #pragma unroll
    for (int m = 16; m >= 1; m >>= 1) p += __shfl_xor(p, m);
    if (o == 0) out[node] = 1.0f / (1.0f + expf(-(p + outb[0])));
}

// ---------------------------------------------------------------------------
extern "C" void kernel_launch(void* const* d_in, const int* in_sizes, int n_in,
                              void* d_out, int out_size, void* d_ws, size_t ws_size,
                              hipStream_t stream)
{
    const float* x    = (const float*)d_in[0];
    const float* aux  = (const float*)d_in[1];
    const int*   ei   = (const int*)  d_in[2];
    const float* c1w  = (const float*)d_in[3];
    const float* c1b  = (const float*)d_in[4];
    const float* c2w  = (const float*)d_in[5];
    const float* c2b  = (const float*)d_in[6];
    const float* few  = (const float*)d_in[7];
    const float* feb  = (const float*)d_in[8];
    const float* g1w  = (const float*)d_in[9];
    const float* g1b  = (const float*)d_in[10];
    const float* g2w  = (const float*)d_in[11];
    const float* g2b  = (const float*)d_in[12];
    const float* fcw  = (const float*)d_in[13];
    const float* fcb  = (const float*)d_in[14];
    const float* outw = (const float*)d_in[15];
    const float* outb = (const float*)d_in[16];
    float* out = (float*)d_out;

    const int n = in_sizes[0] / 64;

    float* ws     = (float*)d_ws;
    float* sig    = ws;
    float* h      = sig + (size_t)n * 32;
    float* acc    = h   + (size_t)n * 64;
    float* outdeg = acc + (size_t)n * 64;
    float* indeg  = outdeg + n;
    float* dis    = indeg + n;
    float* att1   = dis + n;
    float* att2   = att1 + n;

    const dim3 b256(256);
    const int gN  = (n + 255) / 256;
    const int gNM = (int)(((size_t)n * 64 + 255) / 256);
    const int gNH = (int)(((size_t)n * 32 + 255) / 256);

    fe_kernel<<<n, b256, 0, stream>>>(x, c1w, c1b, c2w, c2b, few, feb, sig, n);

    zero_k<<<(2 * n + 255) / 256, b256, 0, stream>>>(outdeg, 2 * n);
    count_k<<<gN, b256, 0, stream>>>(ei, outdeg, indeg, n);
    prep_k<<<gN, b256, 0, stream>>>(indeg, dis, n);
    att_k<<<gN, b256, 0, stream>>>(aux, ei, outdeg, att1, att2, n);

    mm_k<<<gNM, b256, 0, stream>>>(sig, g1w, h, n, 32);
    accinit_k<<<gNM, b256, 0, stream>>>(h, dis, g1b, acc, n);
    scatter_k<<<gNM, b256, 0, stream>>>(h, ei, dis, acc, n);
    fin_k<<<gNM, b256, 0, stream>>>(acc, att1, n);

    mm_k<<<gNM, b256, 0, stream>>>(acc, g2w, h, n, 64);
    accinit_k<<<gNM, b256, 0, stream>>>(h, dis, g2b, acc, n);
    scatter_k<<<gNM, b256, 0, stream>>>(h, ei, dis, acc, n);
    fin_k<<<gNM, b256, 0, stream>>>(acc, att2, n);

    head_k<<<gNH, b256, 0, stream>>>(acc, fcw, fcb, outw, outb, out, n);
}

// Round 3
// 287.005 us; speedup vs baseline: 10.3438x; 3.2581x over previous
//
#include <hip/hip_runtime.h>
#include <math.h>

typedef float f32x4 __attribute__((ext_vector_type(4)));
typedef __bf16 bf16x8 __attribute__((ext_vector_type(8)));
typedef unsigned short ushort8 __attribute__((ext_vector_type(8)));
typedef unsigned short ushort4v __attribute__((ext_vector_type(4)));

static __device__ __forceinline__ unsigned short f2bf(float f) {
    // round-to-nearest-even bf16
    unsigned int u = __builtin_bit_cast(unsigned int, f);
    unsigned int lsb = (u >> 16) & 1u;
    u += 0x7fffu + lsb;
    return (unsigned short)(u >> 16);
}

// ---------------------------------------------------------------------------
// fe: persistent waves; each wave processes whole nodes in a grid-stride loop.
// conv1 fp32 VALU -> hT bf16 ; conv2 = 96 MFMA/node (B-frags in VGPR) ;
// overlapping pool in-register ; raw pool sums (bf16) -> global [n][256].
// ---------------------------------------------------------------------------
__global__ __launch_bounds__(256, 3) void fe_kernel(
    const float* __restrict__ x,
    const float* __restrict__ w1, const float* __restrict__ b1,
    const float* __restrict__ w2, const float* __restrict__ b2,
    unsigned short* __restrict__ poolbf, int n)
{
    __shared__ float w1t[10][32];                 // [tap 0..8 | 9=bias][c]
    __shared__ unsigned short hT[4][100][40];     // per-wave padded 10x10 x 32ci bf16
    __shared__ float xs[4][104];                  // per-wave padded input

    const int t = threadIdx.x, lane = t & 63, wave = t >> 6;
    const int cl = lane & 15, kg = lane >> 4;

    if (t < 288) w1t[t >> 5][t & 31] = w1[(t & 31) * 9 + (t >> 5)];
    if (t >= 288 && t < 320) w1t[9][t - 288] = b1[t - 288];

    // conv2 weights as B-fragments in registers (once per wave)
    bf16x8 bfr[4][4];
    #pragma unroll
    for (int ct = 0; ct < 4; ++ct)
        #pragma unroll
        for (int tap = 0; tap < 4; ++tap) {
            const float* gp = w2 + (size_t)(ct * 16 + cl) * 128 + kg * 32 + tap;
            ushort8 u;
            #pragma unroll
            for (int e = 0; e < 8; ++e) u[e] = f2bf(gp[e * 4]);
            bfr[ct][tap] = __builtin_bit_cast(bf16x8, u);
        }
    float b2r[4];
    #pragma unroll
    for (int ct = 0; ct < 4; ++ct) b2r[ct] = b2[ct * 16 + cl];

    // zero wave-private pad regions once (interior rewritten every node)
    {
        ushort8 z8 = {0,0,0,0,0,0,0,0};
        for (int r = lane; r < 100; r += 64) {
            const int pi = r / 10, pj = r - 10 * (r / 10);
            if (pi == 0 || pi == 9 || pj == 0 || pj == 9) {
                *reinterpret_cast<ushort8*>(&hT[wave][r][0])  = z8;
                *reinterpret_cast<ushort8*>(&hT[wave][r][8])  = z8;
                *reinterpret_cast<ushort8*>(&hT[wave][r][16]) = z8;
                *reinterpret_cast<ushort8*>(&hT[wave][r][24]) = z8;
                xs[wave][r] = 0.0f;
            }
        }
    }
    __syncthreads();   // w1t ready (once, uniform)

    const int i = lane >> 3, j = lane & 7;        // conv1 pixel for this lane
    const int rr = (i + 1) * 10 + (j + 1);
    const int gw = blockIdx.x * 4 + wave;
    const int nw = gridDim.x * 4;

    for (int node = gw; node < n; node += nw) {
        // ---- input -> xs ----
        xs[wave][rr] = x[(size_t)node * 64 + lane];
        asm volatile("s_waitcnt lgkmcnt(0)" ::: "memory");

        // ---- conv1: 32 channels, fp32, write hT bf16 ----
        float xv[9];
        #pragma unroll
        for (int ki = 0; ki < 3; ++ki)
            #pragma unroll
            for (int kj = 0; kj < 3; ++kj)
                xv[ki * 3 + kj] = xs[wave][(i + ki) * 10 + (j + kj)];

        #pragma unroll
        for (int cp = 0; cp < 4; ++cp) {          // pairs of 4-channel groups
            ushort8 hv;
            #pragma unroll
            for (int half = 0; half < 2; ++half) {
                const int cg = cp * 2 + half;
                f32x4 s = *reinterpret_cast<const f32x4*>(&w1t[9][cg * 4]);
                #pragma unroll
                for (int q = 0; q < 9; ++q) {
                    const f32x4 wq = *reinterpret_cast<const f32x4*>(&w1t[q][cg * 4]);
                    s += xv[q] * wq;
                }
                #pragma unroll
                for (int c = 0; c < 4; ++c)
                    hv[half * 4 + c] = f2bf(fmaxf(s[c], 0.0f));
            }
            *reinterpret_cast<ushort8*>(&hT[wave][rr][cp * 8]) = hv;
        }
        asm volatile("s_waitcnt lgkmcnt(0)" ::: "memory");

        // ---- conv2 (MFMA) + bias + relu + overlapping pool ----
        float pb[4][4];                            // [ct][bin]
        #pragma unroll
        for (int ct = 0; ct < 4; ++ct)
            #pragma unroll
            for (int b = 0; b < 4; ++b) pb[ct][b] = 0.0f;

        #pragma unroll
        for (int mt = 0; mt < 6; ++mt) {
            const int p = mt * 16 + cl;            // A-side pixel row
            const int ia = p / 9, ja = p - ia * 9;
            const int rb = (p < 81) ? (ia * 10 + ja) : 0;

            f32x4 acc[4];
            #pragma unroll
            for (int ct = 0; ct < 4; ++ct)
                acc[ct] = (f32x4){b2r[ct], b2r[ct], b2r[ct], b2r[ct]};

            #pragma unroll
            for (int tap = 0; tap < 4; ++tap) {
                const bf16x8 afr = *reinterpret_cast<const bf16x8*>(
                    &hT[wave][rb + (tap >> 1) * 10 + (tap & 1)][kg * 8]);
                #pragma unroll
                for (int ct = 0; ct < 4; ++ct)
                    acc[ct] = __builtin_amdgcn_mfma_f32_16x16x32_bf16(
                        afr, bfr[ct][tap], acc[ct], 0, 0, 0);
            }

            #pragma unroll
            for (int rg = 0; rg < 4; ++rg) {
                if (mt * 16 + rg >= 81) continue;  // dead for all kg: compile-time skip
                const int pd = mt * 16 + (kg << 2) + rg;
                const int id = pd / 9, jd = pd - id * 9;
                const bool val = pd < 81;
                const float wa = (val && id <= 4 && jd <= 4) ? 1.0f : 0.0f;
                const float wb = (val && id <= 4 && jd >= 4) ? 1.0f : 0.0f;
                const float wc = (val && id >= 4 && jd <= 4) ? 1.0f : 0.0f;
                const float wd = (val && id >= 4 && jd >= 4) ? 1.0f : 0.0f;
                #pragma unroll
                for (int ct = 0; ct < 4; ++ct) {
                    const float v = fmaxf(acc[ct][rg], 0.0f);
                    pb[ct][0] = fmaf(v, wa, pb[ct][0]);
                    pb[ct][1] = fmaf(v, wb, pb[ct][1]);
                    pb[ct][2] = fmaf(v, wc, pb[ct][2]);
                    pb[ct][3] = fmaf(v, wd, pb[ct][3]);
                }
            }
        }

        // reduce across kg groups (butterfly -> every lane has full sums)
        #pragma unroll
        for (int ct = 0; ct < 4; ++ct)
            #pragma unroll
            for (int b = 0; b < 4; ++b) {
                pb[ct][b] += __shfl_xor(pb[ct][b], 16);
                pb[ct][b] += __shfl_xor(pb[ct][b], 32);
            }
        // lane (kg,cl) stores ct=kg  ->  one fully-coalesced dwordx2 per lane
        ushort4v pv;
        #pragma unroll
        for (int b = 0; b < 4; ++b) {
            const float q = (kg == 0) ? pb[0][b] : (kg == 1) ? pb[1][b]
                          : (kg == 2) ? pb[2][b] : pb[3][b];
            pv[b] = f2bf(q);
        }
        *reinterpret_cast<ushort4v*>(poolbf + (size_t)node * 256 + lane * 4) = pv;
    }
}

// ---------------------------------------------------------------------------
// precompute: W1t[64][256] = bf16(0.04 * (fw @ g1w))^T, v1 = fb @ g1w,
//             W2t[64][64]  = bf16(g2w^T)
// ---------------------------------------------------------------------------
__global__ void pre_k(const float* __restrict__ fw, const float* __restrict__ fb,
                      const float* __restrict__ g1w, const float* __restrict__ g2w,
                      unsigned short* __restrict__ W1t, float* __restrict__ v1,
                      unsigned short* __restrict__ W2t)
{
    const int b = blockIdx.x, t = threadIdx.x;
    if (b < 64) {
        float s = 0.0f;
        for (int jj = 0; jj < 32; ++jj) s += fw[t * 32 + jj] * g1w[jj * 64 + b];
        W1t[b * 256 + t] = f2bf(0.04f * s);
    } else {
        const int idx = (b - 64) * 256 + t;
        const int nc = idx >> 6, k = idx & 63;
        W2t[nc * 64 + k] = f2bf(g2w[k * 64 + nc]);
        if (b == 64 && t < 64) {
            float s = 0.0f;
            for (int jj = 0; jj < 32; ++jj) s += fb[jj] * g1w[jj * 64 + t];
            v1[t] = s;
        }
    }
}

// ---------------------------------------------------------------------------
// MFMA GEMM: h[n][64] = A[n][K]_bf16 @ Bt^T (+v) ; Bt is [64][K] bf16.
// One 16-row M-tile per wave.
// ---------------------------------------------------------------------------
template<int NKS, bool HASV>
__global__ __launch_bounds__(256) void mm_k(
    const unsigned short* __restrict__ A, const unsigned short* __restrict__ Bt,
    const float* __restrict__ v1, float* __restrict__ h, int n)
{
    const int lane = threadIdx.x & 63;
    const int cl = lane & 15, kg = lane >> 4;
    const int gw = blockIdx.x * 4 + (threadIdx.x >> 6);
    const int nw = gridDim.x * 4;
    const int K = NKS * 32;
    const int ntiles = (n + 15) >> 4;

    float vv[4];
    #pragma unroll
    for (int nt = 0; nt < 4; ++nt) vv[nt] = HASV ? v1[nt * 16 + cl] : 0.0f;

    for (int mt = gw; mt < ntiles; mt += nw) {
        const int r = min(mt * 16 + cl, n - 1);
        const unsigned short* ar = A + (size_t)r * K + kg * 8;
        f32x4 acc[4];
        #pragma unroll
        for (int nt = 0; nt < 4; ++nt)
            acc[nt] = (f32x4){vv[nt], vv[nt], vv[nt], vv[nt]};
        #pragma unroll
        for (int ks = 0; ks < NKS; ++ks) {
            const bf16x8 afr = *reinterpret_cast<const bf16x8*>(ar + ks * 32);
            #pragma unroll
            for (int nt = 0; nt < 4; ++nt) {
                const bf16x8 bfr = *reinterpret_cast<const bf16x8*>(
                    Bt + (size_t)(nt * 16 + cl) * K + ks * 32 + kg * 8);
                acc[nt] = __builtin_amdgcn_mfma_f32_16x16x32_bf16(afr, bfr, acc[nt], 0, 0, 0);
            }
        }
        #pragma unroll
        for (int nt = 0; nt < 4; ++nt)
            #pragma unroll
            for (int rg = 0; rg < 4; ++rg) {
                const int row = mt * 16 + (kg << 2) + rg;
                if (row < n) h[(size_t)row * 64 + nt * 16 + cl] = acc[nt][rg];
            }
    }
}

// ---------------------------------------------------------------------------
__global__ void zero_k(float* __restrict__ p, int n)
{
    int idx = blockIdx.x * blockDim.x + threadIdx.x;
    if (idx < n) p[idx] = 0.0f;
}

__global__ void count_k(const int* __restrict__ ei, float* __restrict__ outdeg,
                        float* __restrict__ indeg, int m)
{
    int e = blockIdx.x * blockDim.x + threadIdx.x;
    if (e >= m) return;
    atomicAdd(&outdeg[ei[e]], 1.0f);
    atomicAdd(&indeg[ei[m + e]], 1.0f);
}

__global__ void prep_k(const float* __restrict__ indeg, float* __restrict__ dis, int n)
{
    int idx = blockIdx.x * blockDim.x + threadIdx.x;
    if (idx < n) dis[idx] = rsqrtf(indeg[idx] + 1.0f);
}

__global__ void att_k(const float* __restrict__ aux, const int* __restrict__ ei,
                      const float* __restrict__ outdeg,
                      float* __restrict__ att1, float* __restrict__ att2, int m)
{
    int e = blockIdx.x * blockDim.x + threadIdx.x;
    if (e >= m) return;
    const int s = ei[e], d = ei[m + e];
    const float fs = aux[(size_t)s * 3 + 2], fdd = aux[(size_t)d * 3 + 2];
    const float fd = fabsf(fs - fdd);
    att1[e] = (fd == 1.0f) ? (1.0f / fmaxf(outdeg[s], 1.0f)) : 0.0f;
    const float angs = aux[(size_t)s * 3 + 0], rads = aux[(size_t)s * 3 + 1];
    const float angd = aux[(size_t)d * 3 + 0], radd = aux[(size_t)d * 3 + 1];
    const float dx = radd * cosf(angd) - rads * cosf(angs);
    const float dy = radd * sinf(angd) - rads * sinf(angs);
    const float vel = sqrtf(dx * dx + dy * dy + 1e-12f) * 0.5f;
    att2[e] = (fd == 2.0f) ? expf(-vel / 8.5f) : 0.0f;
}

__global__ void accinit_k(const float* __restrict__ h, const float* __restrict__ dis,
                          const float* __restrict__ b, float* __restrict__ acc, int n)
{
    size_t idx = (size_t)blockIdx.x * blockDim.x + threadIdx.x;
    if (idx >= (size_t)n * 64) return;
    const int node = (int)(idx >> 6), k = (int)(idx & 63);
    const float di = dis[node];
    acc[idx] = b[k] + di * di * h[idx];
}

__global__ void scatter_k(const float* __restrict__ h, const int* __restrict__ ei,
                          const float* __restrict__ dis, float* __restrict__ acc, int m)
{
    size_t idx = (size_t)blockIdx.x * blockDim.x + threadIdx.x;
    if (idx >= (size_t)m * 64) return;
    const int e = (int)(idx >> 6), k = (int)(idx & 63);
    const int s = ei[e], d = ei[m + e];
    const float w = dis[s] * dis[d];
    atomicAdd(&acc[(size_t)d * 64 + k], w * h[(size_t)s * 64 + k]);
}

// fin: v = relu(acc*att); write bf16 to xout if given, else fp32 in place
__global__ void fin_k(float* __restrict__ acc, const float* __restrict__ att,
                      unsigned short* __restrict__ xout, int n)
{
    size_t idx = (size_t)blockIdx.x * blockDim.x + threadIdx.x;
    if (idx >= (size_t)n * 64) return;
    const int node = (int)(idx >> 6);
    const float v = fmaxf(acc[idx] * att[node], 0.0f);
    if (xout) xout[idx] = f2bf(v);
    else      acc[idx] = v;
}

__global__ void head_k(const float* __restrict__ x2, const float* __restrict__ fcw,
                       const float* __restrict__ fcb, const float* __restrict__ outw,
                       const float* __restrict__ outb, float* __restrict__ out, int n)
{
    size_t idx = (size_t)blockIdx.x * blockDim.x + threadIdx.x;
    const int node = (int)(idx >> 5), o = (int)(idx & 31);
    if (node >= n) return;
    const float* xr = x2 + (size_t)node * 64;
    float s = fcb[o];
    #pragma unroll
    for (int k = 0; k < 64; ++k) s = fmaf(xr[k], fcw[k * 32 + o], s);
    s = fmaxf(s, 0.0f);
    float p = s * outw[o];
    #pragma unroll
    for (int mk = 16; mk >= 1; mk >>= 1) p += __shfl_xor(p, mk);
    if (o == 0) out[node] = 1.0f / (1.0f + expf(-(p + outb[0])));
}

// ---------------------------------------------------------------------------
extern "C" void kernel_launch(void* const* d_in, const int* in_sizes, int n_in,
                              void* d_out, int out_size, void* d_ws, size_t ws_size,
                              hipStream_t stream)
{
    const float* x    = (const float*)d_in[0];
    const float* aux  = (const float*)d_in[1];
    const int*   ei   = (const int*)  d_in[2];
    const float* c1w  = (const float*)d_in[3];
    const float* c1b  = (const float*)d_in[4];
    const float* c2w  = (const float*)d_in[5];
    const float* c2b  = (const float*)d_in[6];
    const float* few  = (const float*)d_in[7];
    const float* feb  = (const float*)d_in[8];
    const float* g1w  = (const float*)d_in[9];
    const float* g1b  = (const float*)d_in[10];
    const float* g2w  = (const float*)d_in[11];
    const float* g2b  = (const float*)d_in[12];
    const float* fcw  = (const float*)d_in[13];
    const float* fcb  = (const float*)d_in[14];
    const float* outw = (const float*)d_in[15];
    const float* outb = (const float*)d_in[16];
    float* out = (float*)d_out;

    const int n = in_sizes[0] / 64;       // nodes
    const int m = in_sizes[2] / 2;        // edges

    // workspace layout (floats). pool region is overlaid by acc + x1bf after mm1.
    float* ws = (float*)d_ws;
    unsigned short* poolbf = (unsigned short*)ws;            // n*256 bf16 = n*128 f32
    float* acc  = ws;                                        // n*64 f32 (overlay, used after mm1)
    unsigned short* x1bf = (unsigned short*)(ws + (size_t)n * 64);  // n*64 bf16 (overlay)
    float* h    = ws + (size_t)n * 128;                      // n*64 f32
    unsigned short* W1t = (unsigned short*)(ws + (size_t)n * 192);  // 64*256 bf16 = 8192 f32
    float* v1   = ws + (size_t)n * 192 + 8192;               // 64
    unsigned short* W2t = (unsigned short*)(v1 + 64);        // 64*64 bf16 = 2048 f32
    float* outdeg = v1 + 64 + 2048;                          // n
    float* indeg  = outdeg + n;                              // n
    float* dis    = indeg + n;                               // n
    float* att1   = dis + n;                                 // m
    float* att2   = att1 + m;                                // m

    const dim3 b256(256);
    const int gE   = (m + 255) / 256;
    const int gNn  = (n + 255) / 256;
    const int gNM  = (int)(((size_t)n * 64 + 255) / 256);
    const int gEM  = (int)(((size_t)m * 64 + 255) / 256);
    const int gNH  = (int)(((size_t)n * 32 + 255) / 256);
    const int gMM  = (((n + 15) / 16) + 3) / 4;

    pre_k<<<80, b256, 0, stream>>>(few, feb, g1w, g2w, W1t, v1, W2t);
    fe_kernel<<<768, b256, 0, stream>>>(x, c1w, c1b, c2w, c2b, poolbf, n);

    zero_k<<<(2 * n + 255) / 256, b256, 0, stream>>>(outdeg, 2 * n);
    count_k<<<gE, b256, 0, stream>>>(ei, outdeg, indeg, m);
    prep_k<<<gNn, b256, 0, stream>>>(indeg, dis, n);
    att_k<<<gE, b256, 0, stream>>>(aux, ei, outdeg, att1, att2, m);

    // GCN layer 1: h = pool @ W1' (+v1)
    mm_k<8, true><<<gMM, b256, 0, stream>>>(poolbf, W1t, v1, h, n);
    accinit_k<<<gNM, b256, 0, stream>>>(h, dis, g1b, acc, n);
    scatter_k<<<gEM, b256, 0, stream>>>(h, ei, dis, acc, m);
    fin_k<<<gNM, b256, 0, stream>>>(acc, att1, x1bf, n);

    // GCN layer 2: h = x1 @ g2w
    mm_k<2, false><<<gMM, b256, 0, stream>>>(x1bf, W2t, nullptr, h, n);
    accinit_k<<<gNM, b256, 0, stream>>>(h, dis, g2b, acc, n);
    scatter_k<<<gEM, b256, 0, stream>>>(h, ei, dis, acc, m);
    fin_k<<<gNM, b256, 0, stream>>>(acc, att2, nullptr, n);

    head_k<<<gNH, b256, 0, stream>>>(acc, fcw, fcb, outw, outb, out, n);
}